// Round 7
// baseline (1732.121 us; speedup 1.0000x reference)
//
#include <hip/hip_runtime.h>
#include <hip/hip_fp16.h>
#include <stdint.h>

#define BB 8
#define NN 4096
#define ATTRD 16
#define HD 64
#define STEPS 8
#define NODES (BB*NN)      // 32768
#define KPAD 196           // xs row stride in floats (gate-proven)
#define CHUNK 256          // srcs staged per LDS tile
#define NCHUNK (NN/CHUNK)  // 16

typedef _Float16 half8 __attribute__((ext_vector_type(8)));
typedef float floatx4 __attribute__((ext_vector_type(4)));
typedef unsigned long long ull;
typedef unsigned int u32;

// byte (8 adjacency bits) -> half8 of 0.0/1.0
__device__ __forceinline__ half8 expand01(u32 b) {
    union { u32 u[4]; half8 h; } r;
    r.u[0] = ((b & 1u)   ? 0x3C00u : 0u) | ((b & 2u)   ? 0x3C000000u : 0u);
    r.u[1] = ((b & 4u)   ? 0x3C00u : 0u) | ((b & 8u)   ? 0x3C000000u : 0u);
    r.u[2] = ((b & 16u)  ? 0x3C00u : 0u) | ((b & 32u)  ? 0x3C000000u : 0u);
    r.u[3] = ((b & 64u)  ? 0x3C00u : 0u) | ((b & 128u) ? 0x3C000000u : 0u);
    return r.h;
}

// ---------------- init: h = relu(attr @ Wi^T + bi); fp32 master + TRANSPOSED fp16 [batch][ch][node] ----
__global__ __launch_bounds__(256) void init_h_kernel(const float* __restrict__ attr,
                                                     const float* __restrict__ Wi,
                                                     const float* __restrict__ bi,
                                                     float* __restrict__ h,
                                                     _Float16* __restrict__ h16T) {
    __shared__ float hl[64][65];
    int bid = blockIdx.x, tid = threadIdx.x;
    int nodeg0 = bid * 64;                           // 64 nodes per block
    int nl = tid >> 2, cq = tid & 3;
    const float* a = attr + (size_t)(nodeg0 + nl) * ATTRD;
#pragma unroll
    for (int cc = 0; cc < 16; cc++) {
        int c = cq * 16 + cc;
        const float* w = Wi + c * ATTRD;
        float acc = bi[c];
#pragma unroll
        for (int k = 0; k < ATTRD; k++) acc += a[k] * w[k];
        hl[nl][c] = acc > 0.f ? acc : 0.f;
    }
    __syncthreads();
#pragma unroll
    for (int i = 0; i < 16; i++) {                   // fp32 master, coalesced
        int idx = tid + i * 256;
        h[(size_t)nodeg0 * 64 + idx] = hl[idx >> 6][idx & 63];
    }
    {                                                // transposed fp16 mirror
        int ch = tid & 63, seg = tid >> 6;
        int batch = nodeg0 >> 12;
        int nloc = (nodeg0 & 4095) + seg * 16;
        union { ushort us[16]; uint4 u4[2]; } pk;
#pragma unroll
        for (int k = 0; k < 16; k++) {
            __half hv = __float2half(hl[seg * 16 + k][ch]);
            pk.us[k] = *(ushort*)&hv;
        }
        uint4* dst = (uint4*)(h16T + (size_t)batch * 64 * NN + (size_t)ch * NN + nloc);
        dst[0] = pk.u4[0];
        dst[1] = pk.u4[1];
    }
}

// ---------------- weight prep: split-fp16 MFMA B-fragments (r8-proven, unchanged) ----------------
__global__ void wprep_kernel(const float* __restrict__ Wz, const float* __restrict__ Wr,
                             const float* __restrict__ Wh,
                             _Float16* __restrict__ wf_hi, _Float16* __restrict__ wf_lo) {
    int t = blockIdx.x * blockDim.x + threadIdx.x;
    if (t >= 3 * 4 * 6 * 64 * 8) return;
    int mat = t / 12288, rem = t % 12288;
    int tile = rem / 3072, rem2 = rem % 3072;
    int kc = rem2 / 512, rem3 = rem2 % 512;
    int lane = rem3 / 8, j = rem3 % 8;
    int k = kc * 32 + (lane >> 4) * 8 + j;
    int och = tile * 16 + (lane & 15);
    const float* W = (mat == 0) ? Wz : (mat == 1) ? Wr : Wh;
    float v = W[och * 192 + k];
    _Float16 hi = (_Float16)v;
    wf_hi[t] = hi;
    wf_lo[t] = (_Float16)(v - (float)hi);
}

// ---------------- adjacency -> bitmasks: bm[row][64 words over cols], bmT[col][64 words over rows] ----
__global__ __launch_bounds__(256) void adj_bitmask_kernel(const float4* __restrict__ A4,
                                                          ull* __restrict__ bm,
                                                          ull* __restrict__ bmT) {
    __shared__ unsigned char nibs[4][16][64];
    int wave = threadIdx.x >> 6, l = threadIdx.x & 63;
    int row = blockIdx.x * 4 + wave;                 // global row 0..32767
    int rowl = row & 4095;
    int colbase = row & ~4095;                       // batch*4096
    const float4* rp = A4 + (size_t)row * 1024;
    float4 v[16];
#pragma unroll
    for (int t = 0; t < 16; t++) v[t] = rp[t * 64 + l];   // 16 coalesced 1KB loads in flight
#pragma unroll
    for (int t = 0; t < 16; t++) {
        float4 vv = v[t];
        unsigned nib = (vv.x != 0.f ? 1u : 0u) | (vv.y != 0.f ? 2u : 0u) |
                       (vv.z != 0.f ? 4u : 0u) | (vv.w != 0.f ? 8u : 0u);
        nibs[wave][t][l] = (unsigned char)nib;
        if (nib) {                                   // transposed bits via atomicOr (~41/row)
            int cb = 4 * (t * 64 + l);
            float q0 = vv.x, q1 = vv.y, q2 = vv.z, q3 = vv.w;
            ull bit = 1ull << (rowl & 63);
            int wofs = rowl >> 6;
            if (q0 != 0.f) atomicOr(&bmT[(size_t)(colbase + cb + 0) * 64 + wofs], bit);
            if (q1 != 0.f) atomicOr(&bmT[(size_t)(colbase + cb + 1) * 64 + wofs], bit);
            if (q2 != 0.f) atomicOr(&bmT[(size_t)(colbase + cb + 2) * 64 + wofs], bit);
            if (q3 != 0.f) atomicOr(&bmT[(size_t)(colbase + cb + 3) * 64 + wofs], bit);
        }
    }
    __syncthreads();
    // assemble row-major words: thread -> (row r of block, word W); col = 64W + 4k + q <-> nib bit q
    int r = threadIdx.x >> 6, W = threadIdx.x & 63;
    int t = W >> 2, sub = W & 3;
    ull wd = 0;
#pragma unroll
    for (int k = 0; k < 16; k++)
        wd |= (ull)nibs[r][t][sub * 16 + k] << (4 * k);
    bm[(size_t)(blockIdx.x * 4 + r) * 64 + W] = wd;
}

// ---------------- fused step: dense bitmask-MFMA aggregation + per-wave gate MFMA ----------------
// Block = 64 out-nodes (512 blocks). r7: staging relabeled so every global load instruction is
// line-coalesced (g = u*256+tid walks the 32KB chunk linearly) and LDS writes are conflict-free;
// final LDS layout (incl. XOR swizzle) identical to r6, compute path untouched. Register
// double-buffer: chunk c+1 loads in flight during chunk c's MFMAs (T14). bm words hoisted.
__global__ __launch_bounds__(256) void step_kernel(
        const _Float16* __restrict__ hTin, const ull* __restrict__ bm, const ull* __restrict__ bmT,
        const _Float16* __restrict__ wf_hi, const _Float16* __restrict__ wf_lo,
        const float* __restrict__ bz, const float* __restrict__ br, const float* __restrict__ bh,
        float* __restrict__ h, _Float16* __restrict__ hTout) {
    __shared__ __attribute__((aligned(16))) float xs[64][KPAD];   // 50.2 KB; first 32 KB doubles as hT stage
    char* smem = (char*)&xs[0][0];
    int bid = blockIdx.x;
    int batch = bid >> 6, tile = bid & 63;
    int tid = threadIdx.x;
    int w = tid >> 6, l = tid & 63;
    int rl = l & 15, kg = l >> 4;
    int nb = tile * 64;
    const uint4* hin4 = (const uint4*)(hTin + (size_t)batch * 64 * NN);
    int growbase = batch * 4096 + nb + w * 16 + rl;             // this lane's bm row
    const uint2* bmrow  = (const uint2*)(bm  + (size_t)growbase * 64);
    const uint2* bmTrow = (const uint2*)(bmT + (size_t)growbase * 64);

    floatx4 accI[4], accO[4];
#pragma unroll
    for (int ct = 0; ct < 4; ct++) { accI[ct] = {0.f,0.f,0.f,0.f}; accO[ct] = {0.f,0.f,0.f,0.f}; }

    auto compute = [&](uint2 wA, uint2 wB) {
#pragma unroll
        for (int kc = 0; kc < 8; ++kc) {
            u32 sA = (kc & 1) ? wA.y : wA.x;
            u32 sB = (kc & 1) ? wB.y : wB.x;
            int srcl = rl + ((kc >> 1) << 4);                   // lane holding needed word
            u32 bA = ((u32)__shfl((int)sA, srcl) >> (kg * 8)) & 255u;
            u32 bB = ((u32)__shfl((int)sB, srcl) >> (kg * 8)) & 255u;
            half8 aI = expand01(bA);
            half8 aO = expand01(bB);
#pragma unroll
            for (int ct = 0; ct < 4; ++ct) {
                int ch = ct * 16 + rl;
                int bo = (ch * (CHUNK * 2) + (kc * 32 + kg * 8) * 2) ^ ((ch & 7) << 4);
                half8 bf = *(const half8*)(smem + bo);          // B-frag shared by both dirs
                accI[ct] = __builtin_amdgcn_mfma_f32_16x16x32_f16(aI, bf, accI[ct], 0, 0, 0);
                accO[ct] = __builtin_amdgcn_mfma_f32_16x16x32_f16(aO, bf, accO[ct], 0, 0, 0);
            }
        }
    };

    uint4 rA[8], rB[8];
#pragma unroll
    for (int u = 0; u < 8; u++) {                               // prologue: chunk 0 -> regs
        int g = u * 256 + tid; int ch = g >> 5;
        rA[u] = hin4[ch * 512 + (g & 31)];
    }
    for (int c = 0; c < NCHUNK; c += 2) {
        __syncthreads();                                        // stage region free
#pragma unroll
        for (int u = 0; u < 8; u++) {                           // conflict-free LDS write (layout = r6)
            int g = u * 256 + tid;
            *(uint4*)(smem + ((g * 16) ^ (((g >> 5) & 7) << 4))) = rA[u];
        }
        uint2 wA0 = bmrow[c * 4 + kg], wB0 = bmTrow[c * 4 + kg];
        if (c + 1 < NCHUNK) {
#pragma unroll
            for (int u = 0; u < 8; u++) {                       // prefetch c+1 (in flight under MFMAs)
                int g = u * 256 + tid; int ch = g >> 5;
                rB[u] = hin4[ch * 512 + (c + 1) * 32 + (g & 31)];
            }
        }
        __syncthreads();
        compute(wA0, wB0);
        __syncthreads();
#pragma unroll
        for (int u = 0; u < 8; u++) {
            int g = u * 256 + tid;
            *(uint4*)(smem + ((g * 16) ^ (((g >> 5) & 7) << 4))) = rB[u];
        }
        uint2 wA1 = bmrow[(c + 1) * 4 + kg], wB1 = bmTrow[(c + 1) * 4 + kg];
        if (c + 2 < NCHUNK) {
#pragma unroll
            for (int u = 0; u < 8; u++) {
                int g = u * 256 + tid; int ch = g >> 5;
                rA[u] = hin4[ch * 512 + (c + 2) * 32 + (g & 31)];
            }
        }
        __syncthreads();
        compute(wA1, wB1);
    }
    __syncthreads();                                            // stage region becomes xs

    // ---------- write aggregation -> xs rows (own wave's 16 nodes) + fp32 h slot ----------
#pragma unroll
    for (int ct = 0; ct < 4; ++ct)
#pragma unroll
        for (int rg = 0; rg < 4; ++rg) {
            int rowi = w * 16 + kg * 4 + rg;                    // D row=(lane>>4)*4+rg
            xs[rowi][ct * 16 + rl]      = accI[ct][rg];
            xs[rowi][64 + ct * 16 + rl] = accO[ct][rg];
        }
    {
        int gnode0 = batch * 4096 + nb + w * 16;
#pragma unroll
        for (int r = 0; r < 16; r++)
            xs[w * 16 + r][128 + l] = h[(size_t)(gnode0 + r) * 64 + l];
    }

    // ---------- gate: per-wave split-fp16 MFMA over own 16 nodes, all 64 ch ----------
    const half8* WH = (const half8*)wf_hi;
    const half8* WL = (const half8*)wf_lo;
    int m = rl, q = kg;
    int r0 = w * 16;
    floatx4 accz[4], accr[4];
#pragma unroll
    for (int ct = 0; ct < 4; ct++) { accz[ct] = {0.f,0.f,0.f,0.f}; accr[ct] = {0.f,0.f,0.f,0.f}; }
#pragma unroll
    for (int kc = 0; kc < 6; kc++) {
        const float* xr = &xs[r0 + m][kc * 32 + q * 8];
        float4 xa = *(const float4*)xr;
        float4 xb = *(const float4*)(xr + 4);
        float xv[8] = {xa.x, xa.y, xa.z, xa.w, xb.x, xb.y, xb.z, xb.w};
        half8 ahi, alo;
#pragma unroll
        for (int j = 0; j < 8; j++) {
            _Float16 hj = (_Float16)xv[j];
            ahi[j] = hj;
            alo[j] = (_Float16)(xv[j] - (float)hj);
        }
#pragma unroll
        for (int ct = 0; ct < 4; ct++) {
            half8 bzh = WH[((0 * 4 + ct) * 6 + kc) * 64 + l];
            half8 bzl = WL[((0 * 4 + ct) * 6 + kc) * 64 + l];
            half8 brh = WH[((1 * 4 + ct) * 6 + kc) * 64 + l];
            half8 brl = WL[((1 * 4 + ct) * 6 + kc) * 64 + l];
            accz[ct] = __builtin_amdgcn_mfma_f32_16x16x32_f16(ahi, bzh, accz[ct], 0, 0, 0);
            accz[ct] = __builtin_amdgcn_mfma_f32_16x16x32_f16(alo, bzh, accz[ct], 0, 0, 0);
            accz[ct] = __builtin_amdgcn_mfma_f32_16x16x32_f16(ahi, bzl, accz[ct], 0, 0, 0);
            accr[ct] = __builtin_amdgcn_mfma_f32_16x16x32_f16(ahi, brh, accr[ct], 0, 0, 0);
            accr[ct] = __builtin_amdgcn_mfma_f32_16x16x32_f16(alo, brh, accr[ct], 0, 0, 0);
            accr[ct] = __builtin_amdgcn_mfma_f32_16x16x32_f16(ahi, brl, accr[ct], 0, 0, 0);
        }
    }
    float zreg[4][4], hvreg[4][4];
#pragma unroll
    for (int ct = 0; ct < 4; ct++) {
        float bzv = bz[ct * 16 + rl], brv = br[ct * 16 + rl];
#pragma unroll
        for (int rg = 0; rg < 4; rg++) {
            float z  = 1.f / (1.f + __expf(-(accz[ct][rg] + bzv)));
            float rr = 1.f / (1.f + __expf(-(accr[ct][rg] + brv)));
            float hv = xs[r0 + q * 4 + rg][128 + ct * 16 + rl];
            zreg[ct][rg] = z; hvreg[ct][rg] = hv;
            xs[r0 + q * 4 + rg][128 + ct * 16 + rl] = rr * hv;  // same lane reads then writes this slot
        }
    }
    floatx4 acch[4];
#pragma unroll
    for (int ct = 0; ct < 4; ct++) acch[ct] = {0.f,0.f,0.f,0.f};
#pragma unroll
    for (int kc = 0; kc < 6; kc++) {
        const float* xr = &xs[r0 + m][kc * 32 + q * 8];
        float4 xa = *(const float4*)xr;
        float4 xb = *(const float4*)(xr + 4);
        float xv[8] = {xa.x, xa.y, xa.z, xa.w, xb.x, xb.y, xb.z, xb.w};
        half8 ahi, alo;
#pragma unroll
        for (int j = 0; j < 8; j++) {
            _Float16 hj = (_Float16)xv[j];
            ahi[j] = hj;
            alo[j] = (_Float16)(xv[j] - (float)hj);
        }
#pragma unroll
        for (int ct = 0; ct < 4; ct++) {
            half8 bhh = WH[((2 * 4 + ct) * 6 + kc) * 64 + l];
            half8 bhl = WL[((2 * 4 + ct) * 6 + kc) * 64 + l];
            acch[ct] = __builtin_amdgcn_mfma_f32_16x16x32_f16(ahi, bhh, acch[ct], 0, 0, 0);
            acch[ct] = __builtin_amdgcn_mfma_f32_16x16x32_f16(alo, bhh, acch[ct], 0, 0, 0);
            acch[ct] = __builtin_amdgcn_mfma_f32_16x16x32_f16(ahi, bhl, acch[ct], 0, 0, 0);
        }
    }
#pragma unroll
    for (int ct = 0; ct < 4; ct++) {
        float bhv = bh[ct * 16 + rl];
#pragma unroll
        for (int rg = 0; rg < 4; rg++) {
            float pre = acch[ct][rg] + bhv;
            float th = 2.f / (1.f + __expf(-2.f * pre)) - 1.f;
            float hv = hvreg[ct][rg];
            xs[r0 + q * 4 + rg][ct * 16 + rl] = hv + zreg[ct][rg] * (th - hv);  // stage h'
        }
    }
    {   // fp32 h write (own rows, coalesced)
        int gnode0 = batch * 4096 + nb + w * 16;
#pragma unroll
        for (int r = 0; r < 16; r++)
            h[(size_t)(gnode0 + r) * 64 + l] = xs[r0 + r][l];
    }
    __syncthreads();
    {   // transposed fp16 epilogue (block-coalesced 32B chunks)
        int ch = tid & 63, seg = tid >> 6;
        union { ushort us[16]; uint4 u4[2]; } pk;
#pragma unroll
        for (int k = 0; k < 16; k++) {
            __half hv = __float2half(xs[seg * 16 + k][ch]);
            pk.us[k] = *(ushort*)&hv;
        }
        uint4* dst = (uint4*)(hTout + (size_t)batch * 64 * NN + (size_t)ch * NN + nb + seg * 16);
        dst[0] = pk.u4[0];
        dst[1] = pk.u4[1];
    }
}

// ---------------- output: out = h @ Wo^T + bo ----------------
__global__ void out_kernel(const float* __restrict__ h, const float* __restrict__ Wo,
                           const float* __restrict__ bo, float* __restrict__ out) {
    int wid = (blockIdx.x * blockDim.x + threadIdx.x) >> 6;
    int l = threadIdx.x & 63;
    if (wid >= NODES) return;
    float p = h[(wid << 6) | l] * Wo[l];
#pragma unroll
    for (int off = 32; off > 0; off >>= 1) p += __shfl_down(p, off);
    if (l == 0) out[wid] = p + bo[0];
}

extern "C" void kernel_launch(void* const* d_in, const int* in_sizes, int n_in,
                              void* d_out, int out_size, void* d_ws, size_t ws_size,
                              hipStream_t stream) {
    const float* attr = (const float*)d_in[0];
    const float* adj  = (const float*)d_in[1];
    const float* Wi   = (const float*)d_in[2];
    const float* bi   = (const float*)d_in[3];
    const float* Wz   = (const float*)d_in[4];
    const float* bz   = (const float*)d_in[5];
    const float* Wr   = (const float*)d_in[6];
    const float* br   = (const float*)d_in[7];
    const float* Wh   = (const float*)d_in[8];
    const float* bh   = (const float*)d_in[9];
    const float* Wo   = (const float*)d_in[10];
    const float* bo   = (const float*)d_in[11];
    float* out = (float*)d_out;

    char* ws = (char*)d_ws;
    size_t off = 0;
    auto carve = [&](size_t bytes) { void* p = ws + off; off = (off + bytes + 255) & ~(size_t)255; return p; };
    float* h        = (float*)carve((size_t)NODES * HD * 4);          // 8.4 MB
    _Float16* hTa   = (_Float16*)carve((size_t)NODES * HD * 2);       // 4.2 MB transposed [b][ch][n]
    _Float16* hTb   = (_Float16*)carve((size_t)NODES * HD * 2);       // 4.2 MB
    _Float16* wf_hi = (_Float16*)carve(3 * 4 * 6 * 64 * 8 * 2);       // 73.7 KB
    _Float16* wf_lo = (_Float16*)carve(3 * 4 * 6 * 64 * 8 * 2);       // 73.7 KB
    ull* bm         = (ull*)carve((size_t)NODES * 64 * 8);            // 16.8 MB row bitmask
    ull* bmT        = (ull*)carve((size_t)NODES * 64 * 8);            // 16.8 MB col bitmask

    hipMemsetAsync(bmT, 0, (size_t)NODES * 64 * 8, stream);           // bm fully written, no memset

    init_h_kernel<<<NODES / 64, 256, 0, stream>>>(attr, Wi, bi, h, hTa);
    wprep_kernel<<<(3 * 4 * 6 * 64 * 8 + 255) / 256, 256, 0, stream>>>(Wz, Wr, Wh, wf_hi, wf_lo);
    adj_bitmask_kernel<<<NODES / 4, 256, 0, stream>>>((const float4*)adj, bm, bmT);

    for (int step = 0; step < STEPS; ++step) {
        const _Float16* hin = (step & 1) ? hTb : hTa;
        _Float16* hout      = (step & 1) ? hTa : hTb;
        step_kernel<<<NODES / 64, 256, 0, stream>>>(
            hin, bm, bmT, wf_hi, wf_lo, bz, br, bh, h, hout);
    }
    out_kernel<<<NODES * HD / 256, 256, 0, stream>>>(h, Wo, bo, out);
}

// Round 8
// 1163.165 us; speedup vs baseline: 1.4891x; 1.4891x over previous
//
#include <hip/hip_runtime.h>
#include <hip/hip_fp16.h>
#include <stdint.h>

#define BB 8
#define NN 4096
#define ATTRD 16
#define HD 64
#define STEPS 8
#define NODES (BB*NN)      // 32768
#define ECAP 96            // nnz/row ~ Poisson(41); P(>=96) astronomically small
#define KPAD 196           // xs_t row stride in floats

typedef _Float16 half8 __attribute__((ext_vector_type(8)));
typedef float floatx4 __attribute__((ext_vector_type(4)));
typedef unsigned long long ull;

// ---------------- init: h = relu(attr @ Wi^T + bi); fp32 master + fp16 mirrors + zero pad rows ----
__global__ void init_h_kernel(const float* __restrict__ attr, const float* __restrict__ Wi,
                              const float* __restrict__ bi, float* __restrict__ h,
                              __half* __restrict__ h16a, __half* __restrict__ h16b) {
    int idx = blockIdx.x * blockDim.x + threadIdx.x;   // node*64 + l
    if (idx >= (NODES + 1) * HD) return;
    if (idx >= NODES * HD) {                           // dummy row (index NODES): zeros in BOTH buffers
        h16a[idx] = __float2half(0.f);
        h16b[idx] = __float2half(0.f);
        return;
    }
    int node = idx >> 6, l = idx & 63;
    const float* a = attr + node * ATTRD;
    const float* w = Wi + l * ATTRD;
    float acc = bi[l];
#pragma unroll
    for (int k = 0; k < ATTRD; k++) acc += a[k] * w[k];
    float r = acc > 0.f ? acc : 0.f;
    h[idx] = r;
    h16a[idx] = __float2half(r);
}

// ---------------- weight prep: split-fp16 MFMA B-fragments (r8-proven) ----------------
__global__ void wprep_kernel(const float* __restrict__ Wz, const float* __restrict__ Wr,
                             const float* __restrict__ Wh,
                             _Float16* __restrict__ wf_hi, _Float16* __restrict__ wf_lo) {
    int t = blockIdx.x * blockDim.x + threadIdx.x;
    if (t >= 3 * 4 * 6 * 64 * 8) return;
    int mat = t / 12288, rem = t % 12288;
    int tile = rem / 3072, rem2 = rem % 3072;
    int kc = rem2 / 512, rem3 = rem2 % 512;
    int lane = rem3 / 8, j = rem3 % 8;
    int k = kc * 32 + (lane >> 4) * 8 + j;
    int och = tile * 16 + (lane & 15);
    const float* W = (mat == 0) ? Wz : (mat == 1) ? Wr : Wh;
    float v = W[och * 192 + k];
    _Float16 hi = (_Float16)v;
    wf_hi[t] = hi;
    wf_lo[t] = (_Float16)(v - (float)hi);
}

// ---------------- ELL build: one wave per row; in-edges atomic-free, out-edges folded (r11) ----
__global__ __launch_bounds__(256) void count_rows_kernel(const float4* __restrict__ A4,
                                                         int* __restrict__ cnt_in,
                                                         int* __restrict__ edge_in,
                                                         int* __restrict__ cnt_out,
                                                         int* __restrict__ edge_out) {
    int wave = threadIdx.x >> 6, l = threadIdx.x & 63;
    int row = blockIdx.x * 4 + wave;                   // 0..32767
    const float4* rp = A4 + (size_t)row * 1024;
    ull mask_lt = (l == 63) ? ~0ull >> 1 : ((1ull << (l + 1)) - 1) >> 1; // bits < l
    float4 v[16];
#pragma unroll
    for (int t = 0; t < 16; t++) v[t] = rp[t * 64 + l];   // 16 coalesced 1KB loads in flight
    int colbase = (row >> 12) << 12;                      // batch * 4096
    int run = 0;
    int* erow = edge_in + row * ECAP;
#pragma unroll
    for (int t = 0; t < 16; t++) {
        ull b0 = __ballot(v[t].x != 0.f);
        ull b1 = __ballot(v[t].y != 0.f);
        ull b2 = __ballot(v[t].z != 0.f);
        ull b3 = __ballot(v[t].w != 0.f);
        int pre = __popcll(b0 & mask_lt) + __popcll(b1 & mask_lt) +
                  __popcll(b2 & mask_lt) + __popcll(b3 & mask_lt);
        float vv[4] = {v[t].x, v[t].y, v[t].z, v[t].w};
        int jbase = (t * 64 + l) * 4;
        int inner = 0;
#pragma unroll
        for (int q = 0; q < 4; q++) {
            if (vv[q] != 0.f) {
                int col = colbase | (jbase + q);
                int slot = run + pre + inner;
                if (slot < ECAP) erow[slot] = col;
                inner++;
                int s2 = atomicAdd(&cnt_out[col], 1);      // distinct cols per lane
                if (s2 < ECAP) edge_out[col * ECAP + s2] = row;
            }
        }
        run += __popcll(b0) + __popcll(b1) + __popcll(b2) + __popcll(b3);
    }
    if (l == 0) cnt_in[row] = run;
}

// ---------------- fused step: aggregation (LDS xs_t) + gates (split-fp16 MFMA) ----------------
// Block = 16 nodes. Phase A: exact r3 gather loop + wave-uniform direction-skip (r8-iso):
// when s >= ni (or no), that direction's gathers/adds are skipped — they were +0.0f from the
// dummy row, so numerics are unchanged. Phase B: r8-proven gate math. h16 double-buffered.
__global__ __launch_bounds__(256) void step_kernel(
        const uint4* __restrict__ h4,                    // prev-step h16 (read, all nodes)
        const int* __restrict__ cnt_in, const int* __restrict__ edge_in,
        const int* __restrict__ cnt_out, const int* __restrict__ edge_out,
        const _Float16* __restrict__ wf_hi, const _Float16* __restrict__ wf_lo,
        const float* __restrict__ bz, const float* __restrict__ br,
        const float* __restrict__ bh,
        float* __restrict__ h,                           // fp32 master (block-local rows only)
        __half* __restrict__ h16o) {                     // next-step h16 (write)
    __shared__ float xs_t[16][KPAD];                     // 12.5 KB
    int bid = blockIdx.x;
    int base = ((bid & 7) << 12) | ((bid >> 3) << 4);    // XCD-swizzled node base (batch=bid&7)
    int tid = threadIdx.x;
    int wave = tid >> 6, l = tid & 63;

    // ---------- phase A: aggregation, one wave -> 4 nodes -> xs_t rows wave*4..wave*4+3 ----------
    {
        int sub = l >> 3;                                // edge slot within volley of 8
        int part = l & 7;                                // 16B chunk within 128B row
        for (int nn = 0; nn < 4; nn++) {
            int row = wave * 4 + nn;
            int node = base + row;
            int ni = cnt_in[node];  if (ni > ECAP) ni = ECAP;
            int no = cnt_out[node]; if (no > ECAP) no = ECAP;
            const int* ei = edge_in + node * ECAP;
            const int* eo = edge_out + node * ECAP;
            int ei0 = ei[l], ei1 = ei[64 + (l & 31)];
            int eo0 = eo[l], eo1 = eo[64 + (l & 31)];
            float hslot = h[(node << 6) | l];            // fp32 master h (own rows only)
            float ai0 = 0.f, ai1 = 0.f, ai2 = 0.f, ai3 = 0.f, ai4 = 0.f, ai5 = 0.f, ai6 = 0.f, ai7 = 0.f;
            float ao0 = 0.f, ao1 = 0.f, ao2 = 0.f, ao3 = 0.f, ao4 = 0.f, ao5 = 0.f, ao6 = 0.f, ao7 = 0.f;
            int nmax = ni > no ? ni : no;
            for (int s = 0; s < nmax; s += 16) {         // 16 slots/iter: up to 4 gathers in flight
                int ila = s + sub, ilb = s + 8 + sub;
                bool din = s < ni, dout = s < no;        // wave-uniform; skipped adds were +0.0f
                if (din) {
                    int gia = (ila < 64) ? __shfl(ei0, ila) : __shfl(ei1, ila - 64);
                    int gib = (ilb < 64) ? __shfl(ei0, ilb) : __shfl(ei1, ilb - 64);
                    gia = (ila < ni) ? gia : NODES;      // dummy zero row
                    gib = (ilb < ni) ? gib : NODES;
                    uint4 gA = h4[(gia << 3) | part];
                    uint4 gB = h4[(gib << 3) | part];
                    float2 pA0 = __half22float2(*(__half2*)&gA.x);
                    float2 pA1 = __half22float2(*(__half2*)&gA.y);
                    float2 pA2 = __half22float2(*(__half2*)&gA.z);
                    float2 pA3 = __half22float2(*(__half2*)&gA.w);
                    ai0 += pA0.x; ai1 += pA0.y; ai2 += pA1.x; ai3 += pA1.y;
                    ai4 += pA2.x; ai5 += pA2.y; ai6 += pA3.x; ai7 += pA3.y;
                    float2 pB0 = __half22float2(*(__half2*)&gB.x);
                    float2 pB1 = __half22float2(*(__half2*)&gB.y);
                    float2 pB2 = __half22float2(*(__half2*)&gB.z);
                    float2 pB3 = __half22float2(*(__half2*)&gB.w);
                    ai0 += pB0.x; ai1 += pB0.y; ai2 += pB1.x; ai3 += pB1.y;
                    ai4 += pB2.x; ai5 += pB2.y; ai6 += pB3.x; ai7 += pB3.y;
                }
                if (dout) {
                    int goa = (ila < 64) ? __shfl(eo0, ila) : __shfl(eo1, ila - 64);
                    int gob = (ilb < 64) ? __shfl(eo0, ilb) : __shfl(eo1, ilb - 64);
                    goa = (ila < no) ? goa : NODES;
                    gob = (ilb < no) ? gob : NODES;
                    uint4 gC = h4[(goa << 3) | part];
                    uint4 gD = h4[(gob << 3) | part];
                    float2 pC0 = __half22float2(*(__half2*)&gC.x);
                    float2 pC1 = __half22float2(*(__half2*)&gC.y);
                    float2 pC2 = __half22float2(*(__half2*)&gC.z);
                    float2 pC3 = __half22float2(*(__half2*)&gC.w);
                    ao0 += pC0.x; ao1 += pC0.y; ao2 += pC1.x; ao3 += pC1.y;
                    ao4 += pC2.x; ao5 += pC2.y; ao6 += pC3.x; ao7 += pC3.y;
                    float2 pD0 = __half22float2(*(__half2*)&gD.x);
                    float2 pD1 = __half22float2(*(__half2*)&gD.y);
                    float2 pD2 = __half22float2(*(__half2*)&gD.z);
                    float2 pD3 = __half22float2(*(__half2*)&gD.w);
                    ao0 += pD0.x; ao1 += pD0.y; ao2 += pD1.x; ao3 += pD1.y;
                    ao4 += pD2.x; ao5 += pD2.y; ao6 += pD3.x; ao7 += pD3.y;
                }
            }
            // reduce over the 8 sub-groups (partners share `part`)
#pragma unroll
            for (int off = 8; off < 64; off <<= 1) {
                ai0 += __shfl_xor(ai0, off); ai1 += __shfl_xor(ai1, off);
                ai2 += __shfl_xor(ai2, off); ai3 += __shfl_xor(ai3, off);
                ai4 += __shfl_xor(ai4, off); ai5 += __shfl_xor(ai5, off);
                ai6 += __shfl_xor(ai6, off); ai7 += __shfl_xor(ai7, off);
                ao0 += __shfl_xor(ao0, off); ao1 += __shfl_xor(ao1, off);
                ao2 += __shfl_xor(ao2, off); ao3 += __shfl_xor(ao3, off);
                ao4 += __shfl_xor(ao4, off); ao5 += __shfl_xor(ao5, off);
                ao6 += __shfl_xor(ao6, off); ao7 += __shfl_xor(ao7, off);
            }
            if (l < 8) {                                 // lane l holds channels l*8..l*8+7
                float4 si0 = {ai0, ai1, ai2, ai3};
                float4 si1 = {ai4, ai5, ai6, ai7};
                float4 so0 = {ao0, ao1, ao2, ao3};
                float4 so1 = {ao4, ao5, ao6, ao7};
                *(float4*)&xs_t[row][l * 8]          = si0;
                *(float4*)&xs_t[row][l * 8 + 4]      = si1;
                *(float4*)&xs_t[row][64 + l * 8]     = so0;
                *(float4*)&xs_t[row][64 + l * 8 + 4] = so1;
            }
            xs_t[row][128 + l] = hslot;                  // fp32 master h slot
        }
    }
    __syncthreads();

    // ---------- phase B: gates via split-fp16 MFMA (r8-proven, fp32-accurate) ----------
    int lane = l;
    int m = lane & 15, q = lane >> 4;
    int ch = wave * 16 + m;                   // global output channel (C/D col=lane&15)
    const half8* WH = (const half8*)wf_hi;
    const half8* WL = (const half8*)wf_lo;

    floatx4 accz = {0.f, 0.f, 0.f, 0.f};
    floatx4 accr = {0.f, 0.f, 0.f, 0.f};
#pragma unroll
    for (int kc = 0; kc < 6; kc++) {
        const float* xr = &xs_t[m][kc * 32 + q * 8];
        float4 xa = *(const float4*)xr;
        float4 xb = *(const float4*)(xr + 4);
        float xv[8] = {xa.x, xa.y, xa.z, xa.w, xb.x, xb.y, xb.z, xb.w};
        half8 ahi, alo;
#pragma unroll
        for (int j = 0; j < 8; j++) {
            _Float16 hj = (_Float16)xv[j];
            ahi[j] = hj;
            alo[j] = (_Float16)(xv[j] - (float)hj);
        }
        half8 bzh = WH[((0 * 4 + wave) * 6 + kc) * 64 + lane];
        half8 bzl = WL[((0 * 4 + wave) * 6 + kc) * 64 + lane];
        half8 brh = WH[((1 * 4 + wave) * 6 + kc) * 64 + lane];
        half8 brl = WL[((1 * 4 + wave) * 6 + kc) * 64 + lane];
        accz = __builtin_amdgcn_mfma_f32_16x16x32_f16(ahi, bzh, accz, 0, 0, 0);
        accz = __builtin_amdgcn_mfma_f32_16x16x32_f16(alo, bzh, accz, 0, 0, 0);
        accz = __builtin_amdgcn_mfma_f32_16x16x32_f16(ahi, bzl, accz, 0, 0, 0);
        accr = __builtin_amdgcn_mfma_f32_16x16x32_f16(ahi, brh, accr, 0, 0, 0);
        accr = __builtin_amdgcn_mfma_f32_16x16x32_f16(alo, brh, accr, 0, 0, 0);
        accr = __builtin_amdgcn_mfma_f32_16x16x32_f16(ahi, brl, accr, 0, 0, 0);
    }
    float bzv = bz[ch], brv = br[ch], bhv = bh[ch];
    float zreg[4], hvreg[4], rh[4];
#pragma unroll
    for (int rg = 0; rg < 4; rg++) {
        int nl = q * 4 + rg;                  // C/D row=(lane>>4)*4+reg -> node
        float z = 1.f / (1.f + __expf(-(accz[rg] + bzv)));
        float r = 1.f / (1.f + __expf(-(accr[rg] + brv)));
        float hv = xs_t[nl][128 + ch];
        zreg[rg] = z; hvreg[rg] = hv; rh[rg] = r * hv;
    }
    __syncthreads();                          // all zr A-frag reads of slots 128+ done
#pragma unroll
    for (int rg = 0; rg < 4; rg++) xs_t[q * 4 + rg][128 + ch] = rh[rg];
    __syncthreads();

    floatx4 acch = {0.f, 0.f, 0.f, 0.f};
#pragma unroll
    for (int kc = 0; kc < 6; kc++) {
        const float* xr = &xs_t[m][kc * 32 + q * 8];
        float4 xa = *(const float4*)xr;
        float4 xb = *(const float4*)(xr + 4);
        float xv[8] = {xa.x, xa.y, xa.z, xa.w, xb.x, xb.y, xb.z, xb.w};
        half8 ahi, alo;
#pragma unroll
        for (int j = 0; j < 8; j++) {
            _Float16 hj = (_Float16)xv[j];
            ahi[j] = hj;
            alo[j] = (_Float16)(xv[j] - (float)hj);
        }
        half8 bhh = WH[((2 * 4 + wave) * 6 + kc) * 64 + lane];
        half8 bhl = WL[((2 * 4 + wave) * 6 + kc) * 64 + lane];
        acch = __builtin_amdgcn_mfma_f32_16x16x32_f16(ahi, bhh, acch, 0, 0, 0);
        acch = __builtin_amdgcn_mfma_f32_16x16x32_f16(alo, bhh, acch, 0, 0, 0);
        acch = __builtin_amdgcn_mfma_f32_16x16x32_f16(ahi, bhl, acch, 0, 0, 0);
    }
    __syncthreads();                          // all hn A-frag reads done before overwrite
#pragma unroll
    for (int rg = 0; rg < 4; rg++) {
        int nl = q * 4 + rg;
        float pre = acch[rg] + bhv;
        float th = 2.f / (1.f + __expf(-2.f * pre)) - 1.f;
        float hv = hvreg[rg];
        xs_t[nl][ch] = hv + zreg[rg] * (th - hv);   // stage h' for coalesced write
    }
    __syncthreads();
    {
        int f = tid * 4;                      // 1024 floats = 16 nodes x 64
        int nl = f >> 6, c = f & 63;
        float4 v = *(const float4*)&xs_t[nl][c];
        int gi = ((base + nl) << 6) | c;
        *(float4*)&h[gi] = v;
        __half2 p0 = {__float2half(v.x), __float2half(v.y)};
        __half2 p1 = {__float2half(v.z), __float2half(v.w)};
        *(__half2*)&h16o[gi] = p0;
        *(__half2*)&h16o[gi + 2] = p1;
    }
}

// ---------------- output: out = h @ Wo^T + bo ----------------
__global__ void out_kernel(const float* __restrict__ h, const float* __restrict__ Wo,
                           const float* __restrict__ bo, float* __restrict__ out) {
    int wid = (blockIdx.x * blockDim.x + threadIdx.x) >> 6;
    int l = threadIdx.x & 63;
    if (wid >= NODES) return;
    float p = h[(wid << 6) | l] * Wo[l];
#pragma unroll
    for (int off = 32; off > 0; off >>= 1) p += __shfl_down(p, off);
    if (l == 0) out[wid] = p + bo[0];
}

extern "C" void kernel_launch(void* const* d_in, const int* in_sizes, int n_in,
                              void* d_out, int out_size, void* d_ws, size_t ws_size,
                              hipStream_t stream) {
    const float* attr = (const float*)d_in[0];
    const float* adj  = (const float*)d_in[1];
    const float* Wi   = (const float*)d_in[2];
    const float* bi   = (const float*)d_in[3];
    const float* Wz   = (const float*)d_in[4];
    const float* bz   = (const float*)d_in[5];
    const float* Wr   = (const float*)d_in[6];
    const float* br   = (const float*)d_in[7];
    const float* Wh   = (const float*)d_in[8];
    const float* bh   = (const float*)d_in[9];
    const float* Wo   = (const float*)d_in[10];
    const float* bo   = (const float*)d_in[11];
    float* out = (float*)d_out;

    char* ws = (char*)d_ws;
    size_t off = 0;
    auto carve = [&](size_t bytes) { void* p = ws + off; off = (off + bytes + 255) & ~(size_t)255; return p; };
    float* h      = (float*)carve((size_t)NODES * HD * 4);            // 8.4 MB
    __half* h16a  = (__half*)carve((size_t)(NODES + 1) * HD * 2);     // 4.2 MB (+dummy row)
    __half* h16b  = (__half*)carve((size_t)(NODES + 1) * HD * 2);     // 4.2 MB (+dummy row)
    _Float16* wf_hi = (_Float16*)carve(3 * 4 * 6 * 64 * 8 * 2);       // 73.7 KB
    _Float16* wf_lo = (_Float16*)carve(3 * 4 * 6 * 64 * 8 * 2);       // 73.7 KB
    int* cnt_in   = (int*)carve((size_t)NODES * 4);
    int* cnt_out  = (int*)carve((size_t)NODES * 4);
    int* edge_in  = (int*)carve((size_t)NODES * ECAP * 4);            // 12.6 MB
    int* edge_out = (int*)carve((size_t)NODES * ECAP * 4);            // 12.6 MB

    hipMemsetAsync(cnt_out, 0, (size_t)NODES * 4, stream);            // cnt_in needs no memset

    init_h_kernel<<<((NODES + 1) * HD + 255) / 256, 256, 0, stream>>>(attr, Wi, bi, h, h16a, h16b);
    wprep_kernel<<<(3 * 4 * 6 * 64 * 8 + 255) / 256, 256, 0, stream>>>(Wz, Wr, Wh, wf_hi, wf_lo);
    count_rows_kernel<<<NODES / 4, 256, 0, stream>>>((const float4*)adj, cnt_in, edge_in,
                                                     cnt_out, edge_out);

    for (int step = 0; step < STEPS; ++step) {
        const __half* hin = (step & 1) ? h16b : h16a;
        __half* hout      = (step & 1) ? h16a : h16b;
        step_kernel<<<NODES / 16, 256, 0, stream>>>(
            (const uint4*)hin, cnt_in, edge_in, cnt_out, edge_out,
            wf_hi, wf_lo, bz, br, bh, h, hout);
    }
    out_kernel<<<NODES * HD / 256, 256, 0, stream>>>(h, Wo, bo, out);
}

// Round 9
// 1129.886 us; speedup vs baseline: 1.5330x; 1.0295x over previous
//
#include <hip/hip_runtime.h>
#include <hip/hip_fp16.h>
#include <stdint.h>

#define BB 8
#define NN 4096
#define ATTRD 16
#define HD 64
#define STEPS 8
#define NODES (BB*NN)      // 32768
#define ECAP 96            // nnz/row ~ Poisson(41); P(>=96) astronomically small
#define KPAD 196           // xs_t row stride in floats

typedef _Float16 half8 __attribute__((ext_vector_type(8)));
typedef float floatx4 __attribute__((ext_vector_type(4)));
typedef unsigned long long ull;

// ---------------- init: h = relu(attr @ Wi^T + bi); fp32 master + fp16 mirrors + zero pad rows ----
__global__ void init_h_kernel(const float* __restrict__ attr, const float* __restrict__ Wi,
                              const float* __restrict__ bi, float* __restrict__ h,
                              __half* __restrict__ h16a, __half* __restrict__ h16b) {
    int idx = blockIdx.x * blockDim.x + threadIdx.x;   // node*64 + l
    if (idx >= (NODES + 1) * HD) return;
    if (idx >= NODES * HD) {                           // dummy row (index NODES): zeros in BOTH buffers
        h16a[idx] = __float2half(0.f);
        h16b[idx] = __float2half(0.f);
        return;
    }
    int node = idx >> 6, l = idx & 63;
    const float* a = attr + node * ATTRD;
    const float* w = Wi + l * ATTRD;
    float acc = bi[l];
#pragma unroll
    for (int k = 0; k < ATTRD; k++) acc += a[k] * w[k];
    float r = acc > 0.f ? acc : 0.f;
    h[idx] = r;
    h16a[idx] = __float2half(r);
}

// ---------------- weight prep: split-fp16 MFMA B-fragments (r8-proven) ----------------
__global__ void wprep_kernel(const float* __restrict__ Wz, const float* __restrict__ Wr,
                             const float* __restrict__ Wh,
                             _Float16* __restrict__ wf_hi, _Float16* __restrict__ wf_lo) {
    int t = blockIdx.x * blockDim.x + threadIdx.x;
    if (t >= 3 * 4 * 6 * 64 * 8) return;
    int mat = t / 12288, rem = t % 12288;
    int tile = rem / 3072, rem2 = rem % 3072;
    int kc = rem2 / 512, rem3 = rem2 % 512;
    int lane = rem3 / 8, j = rem3 % 8;
    int k = kc * 32 + (lane >> 4) * 8 + j;
    int och = tile * 16 + (lane & 15);
    const float* W = (mat == 0) ? Wz : (mat == 1) ? Wr : Wh;
    float v = W[och * 192 + k];
    _Float16 hi = (_Float16)v;
    wf_hi[t] = hi;
    wf_lo[t] = (_Float16)(v - (float)hi);
}

// ---------------- ELL build: one wave per row; in-edges atomic-free, out-edges folded (r11) ----
__global__ __launch_bounds__(256) void count_rows_kernel(const float4* __restrict__ A4,
                                                         int* __restrict__ cnt_in,
                                                         int* __restrict__ edge_in,
                                                         int* __restrict__ cnt_out,
                                                         int* __restrict__ edge_out) {
    int wave = threadIdx.x >> 6, l = threadIdx.x & 63;
    int row = blockIdx.x * 4 + wave;                   // 0..32767
    const float4* rp = A4 + (size_t)row * 1024;
    ull mask_lt = (l == 63) ? ~0ull >> 1 : ((1ull << (l + 1)) - 1) >> 1; // bits < l
    float4 v[16];
#pragma unroll
    for (int t = 0; t < 16; t++) v[t] = rp[t * 64 + l];   // 16 coalesced 1KB loads in flight
    int colbase = (row >> 12) << 12;                      // batch * 4096
    int run = 0;
    int* erow = edge_in + row * ECAP;
#pragma unroll
    for (int t = 0; t < 16; t++) {
        ull b0 = __ballot(v[t].x != 0.f);
        ull b1 = __ballot(v[t].y != 0.f);
        ull b2 = __ballot(v[t].z != 0.f);
        ull b3 = __ballot(v[t].w != 0.f);
        int pre = __popcll(b0 & mask_lt) + __popcll(b1 & mask_lt) +
                  __popcll(b2 & mask_lt) + __popcll(b3 & mask_lt);
        float vv[4] = {v[t].x, v[t].y, v[t].z, v[t].w};
        int jbase = (t * 64 + l) * 4;
        int inner = 0;
#pragma unroll
        for (int q = 0; q < 4; q++) {
            if (vv[q] != 0.f) {
                int col = colbase | (jbase + q);
                int slot = run + pre + inner;
                if (slot < ECAP) erow[slot] = col;
                inner++;
                int s2 = atomicAdd(&cnt_out[col], 1);      // distinct cols per lane
                if (s2 < ECAP) edge_out[col * ECAP + s2] = row;
            }
        }
        run += __popcll(b0) + __popcll(b1) + __popcll(b2) + __popcll(b3);
    }
    if (l == 0) cnt_in[row] = run;
}

// ---------------- fused step: aggregation (LDS xs_t) + gates (split-fp16 MFMA) ----------------
// Block = 16 nodes. Phase A: each wave aggregates its 4 nodes straight into xs_t.
// Phase B: the r8-proven gate math out of LDS. h16 double-buffered across steps
// (phase-B writes would otherwise race other blocks' phase-A gathers of prev-step h16).
__global__ __launch_bounds__(256) void step_kernel(
        const uint4* __restrict__ h4,                    // prev-step h16 (read, all nodes)
        const int* __restrict__ cnt_in, const int* __restrict__ edge_in,
        const int* __restrict__ cnt_out, const int* __restrict__ edge_out,
        const _Float16* __restrict__ wf_hi, const _Float16* __restrict__ wf_lo,
        const float* __restrict__ bz, const float* __restrict__ br,
        const float* __restrict__ bh,
        float* __restrict__ h,                           // fp32 master (block-local rows only)
        __half* __restrict__ h16o) {                     // next-step h16 (write)
    __shared__ float xs_t[16][KPAD];                     // 12.5 KB
    int bid = blockIdx.x;
    int base = ((bid & 7) << 12) | ((bid >> 3) << 4);    // XCD-swizzled node base (batch=bid&7)
    int tid = threadIdx.x;
    int wave = tid >> 6, l = tid & 63;

    // ---------- phase A: aggregation, one wave -> 4 nodes -> xs_t rows wave*4..wave*4+3 ----------
    {
        int sub = l >> 3;                                // edge slot within volley of 8
        int part = l & 7;                                // 16B chunk within 128B row
        for (int nn = 0; nn < 4; nn++) {
            int row = wave * 4 + nn;
            int node = base + row;
            int ni = cnt_in[node];  if (ni > ECAP) ni = ECAP;
            int no = cnt_out[node]; if (no > ECAP) no = ECAP;
            const int* ei = edge_in + node * ECAP;
            const int* eo = edge_out + node * ECAP;
            int ei0 = ei[l], ei1 = ei[64 + (l & 31)];
            int eo0 = eo[l], eo1 = eo[64 + (l & 31)];
            float hslot = h[(node << 6) | l];            // fp32 master h (own rows only)
            float ai0 = 0.f, ai1 = 0.f, ai2 = 0.f, ai3 = 0.f, ai4 = 0.f, ai5 = 0.f, ai6 = 0.f, ai7 = 0.f;
            float ao0 = 0.f, ao1 = 0.f, ao2 = 0.f, ao3 = 0.f, ao4 = 0.f, ao5 = 0.f, ao6 = 0.f, ao7 = 0.f;
            int nmax = ni > no ? ni : no;
            for (int s = 0; s < nmax; s += 16) {         // 16 slots/iter: 4 gathers in flight
                int ila = s + sub, ilb = s + 8 + sub;
                int gia = (ila < 64) ? __shfl(ei0, ila) : __shfl(ei1, ila - 64);
                int gib = (ilb < 64) ? __shfl(ei0, ilb) : __shfl(ei1, ilb - 64);
                int goa = (ila < 64) ? __shfl(eo0, ila) : __shfl(eo1, ila - 64);
                int gob = (ilb < 64) ? __shfl(eo0, ilb) : __shfl(eo1, ilb - 64);
                gia = (ila < ni) ? gia : NODES;          // dummy zero row
                gib = (ilb < ni) ? gib : NODES;
                goa = (ila < no) ? goa : NODES;
                gob = (ilb < no) ? gob : NODES;
                uint4 gA = h4[(gia << 3) | part];
                uint4 gB = h4[(gib << 3) | part];
                uint4 gC = h4[(goa << 3) | part];
                uint4 gD = h4[(gob << 3) | part];
                // in-direction: slot ila then ilb (same per-lane order as the 2-kernel version)
                float2 pA0 = __half22float2(*(__half2*)&gA.x);
                float2 pA1 = __half22float2(*(__half2*)&gA.y);
                float2 pA2 = __half22float2(*(__half2*)&gA.z);
                float2 pA3 = __half22float2(*(__half2*)&gA.w);
                ai0 += pA0.x; ai1 += pA0.y; ai2 += pA1.x; ai3 += pA1.y;
                ai4 += pA2.x; ai5 += pA2.y; ai6 += pA3.x; ai7 += pA3.y;
                float2 pB0 = __half22float2(*(__half2*)&gB.x);
                float2 pB1 = __half22float2(*(__half2*)&gB.y);
                float2 pB2 = __half22float2(*(__half2*)&gB.z);
                float2 pB3 = __half22float2(*(__half2*)&gB.w);
                ai0 += pB0.x; ai1 += pB0.y; ai2 += pB1.x; ai3 += pB1.y;
                ai4 += pB2.x; ai5 += pB2.y; ai6 += pB3.x; ai7 += pB3.y;
                float2 pC0 = __half22float2(*(__half2*)&gC.x);
                float2 pC1 = __half22float2(*(__half2*)&gC.y);
                float2 pC2 = __half22float2(*(__half2*)&gC.z);
                float2 pC3 = __half22float2(*(__half2*)&gC.w);
                ao0 += pC0.x; ao1 += pC0.y; ao2 += pC1.x; ao3 += pC1.y;
                ao4 += pC2.x; ao5 += pC2.y; ao6 += pC3.x; ao7 += pC3.y;
                float2 pD0 = __half22float2(*(__half2*)&gD.x);
                float2 pD1 = __half22float2(*(__half2*)&gD.y);
                float2 pD2 = __half22float2(*(__half2*)&gD.z);
                float2 pD3 = __half22float2(*(__half2*)&gD.w);
                ao0 += pD0.x; ao1 += pD0.y; ao2 += pD1.x; ao3 += pD1.y;
                ao4 += pD2.x; ao5 += pD2.y; ao6 += pD3.x; ao7 += pD3.y;
            }
            // reduce over the 8 sub-groups (partners share `part`)
#pragma unroll
            for (int off = 8; off < 64; off <<= 1) {
                ai0 += __shfl_xor(ai0, off); ai1 += __shfl_xor(ai1, off);
                ai2 += __shfl_xor(ai2, off); ai3 += __shfl_xor(ai3, off);
                ai4 += __shfl_xor(ai4, off); ai5 += __shfl_xor(ai5, off);
                ai6 += __shfl_xor(ai6, off); ai7 += __shfl_xor(ai7, off);
                ao0 += __shfl_xor(ao0, off); ao1 += __shfl_xor(ao1, off);
                ao2 += __shfl_xor(ao2, off); ao3 += __shfl_xor(ao3, off);
                ao4 += __shfl_xor(ao4, off); ao5 += __shfl_xor(ao5, off);
                ao6 += __shfl_xor(ao6, off); ao7 += __shfl_xor(ao7, off);
            }
            if (l < 8) {                                 // lane l holds channels l*8..l*8+7
                float4 si0 = {ai0, ai1, ai2, ai3};
                float4 si1 = {ai4, ai5, ai6, ai7};
                float4 so0 = {ao0, ao1, ao2, ao3};
                float4 so1 = {ao4, ao5, ao6, ao7};
                *(float4*)&xs_t[row][l * 8]          = si0;
                *(float4*)&xs_t[row][l * 8 + 4]      = si1;
                *(float4*)&xs_t[row][64 + l * 8]     = so0;
                *(float4*)&xs_t[row][64 + l * 8 + 4] = so1;
            }
            xs_t[row][128 + l] = hslot;                  // fp32 master h slot
        }
    }
    __syncthreads();

    // ---------- phase B: gates via split-fp16 MFMA (r8-proven, fp32-accurate) ----------
    int lane = l;
    int m = lane & 15, q = lane >> 4;
    int ch = wave * 16 + m;                   // global output channel (C/D col=lane&15)
    const half8* WH = (const half8*)wf_hi;
    const half8* WL = (const half8*)wf_lo;

    floatx4 accz = {0.f, 0.f, 0.f, 0.f};
    floatx4 accr = {0.f, 0.f, 0.f, 0.f};
#pragma unroll
    for (int kc = 0; kc < 6; kc++) {
        const float* xr = &xs_t[m][kc * 32 + q * 8];
        float4 xa = *(const float4*)xr;
        float4 xb = *(const float4*)(xr + 4);
        float xv[8] = {xa.x, xa.y, xa.z, xa.w, xb.x, xb.y, xb.z, xb.w};
        half8 ahi, alo;
#pragma unroll
        for (int j = 0; j < 8; j++) {
            _Float16 hj = (_Float16)xv[j];
            ahi[j] = hj;
            alo[j] = (_Float16)(xv[j] - (float)hj);
        }
        half8 bzh = WH[((0 * 4 + wave) * 6 + kc) * 64 + lane];
        half8 bzl = WL[((0 * 4 + wave) * 6 + kc) * 64 + lane];
        half8 brh = WH[((1 * 4 + wave) * 6 + kc) * 64 + lane];
        half8 brl = WL[((1 * 4 + wave) * 6 + kc) * 64 + lane];
        accz = __builtin_amdgcn_mfma_f32_16x16x32_f16(ahi, bzh, accz, 0, 0, 0);
        accz = __builtin_amdgcn_mfma_f32_16x16x32_f16(alo, bzh, accz, 0, 0, 0);
        accz = __builtin_amdgcn_mfma_f32_16x16x32_f16(ahi, bzl, accz, 0, 0, 0);
        accr = __builtin_amdgcn_mfma_f32_16x16x32_f16(ahi, brh, accr, 0, 0, 0);
        accr = __builtin_amdgcn_mfma_f32_16x16x32_f16(alo, brh, accr, 0, 0, 0);
        accr = __builtin_amdgcn_mfma_f32_16x16x32_f16(ahi, brl, accr, 0, 0, 0);
    }
    float bzv = bz[ch], brv = br[ch], bhv = bh[ch];
    float zreg[4], hvreg[4], rh[4];
#pragma unroll
    for (int rg = 0; rg < 4; rg++) {
        int nl = q * 4 + rg;                  // C/D row=(lane>>4)*4+reg -> node
        float z = 1.f / (1.f + __expf(-(accz[rg] + bzv)));
        float r = 1.f / (1.f + __expf(-(accr[rg] + brv)));
        float hv = xs_t[nl][128 + ch];
        zreg[rg] = z; hvreg[rg] = hv; rh[rg] = r * hv;
    }
    __syncthreads();                          // all zr A-frag reads of slots 128+ done
#pragma unroll
    for (int rg = 0; rg < 4; rg++) xs_t[q * 4 + rg][128 + ch] = rh[rg];
    __syncthreads();

    floatx4 acch = {0.f, 0.f, 0.f, 0.f};
#pragma unroll
    for (int kc = 0; kc < 6; kc++) {
        const float* xr = &xs_t[m][kc * 32 + q * 8];
        float4 xa = *(const float4*)xr;
        float4 xb = *(const float4*)(xr + 4);
        float xv[8] = {xa.x, xa.y, xa.z, xa.w, xb.x, xb.y, xb.z, xb.w};
        half8 ahi, alo;
#pragma unroll
        for (int j = 0; j < 8; j++) {
            _Float16 hj = (_Float16)xv[j];
            ahi[j] = hj;
            alo[j] = (_Float16)(xv[j] - (float)hj);
        }
        half8 bhh = WH[((2 * 4 + wave) * 6 + kc) * 64 + lane];
        half8 bhl = WL[((2 * 4 + wave) * 6 + kc) * 64 + lane];
        acch = __builtin_amdgcn_mfma_f32_16x16x32_f16(ahi, bhh, acch, 0, 0, 0);
        acch = __builtin_amdgcn_mfma_f32_16x16x32_f16(alo, bhh, acch, 0, 0, 0);
        acch = __builtin_amdgcn_mfma_f32_16x16x32_f16(ahi, bhl, acch, 0, 0, 0);
    }
    __syncthreads();                          // all hn A-frag reads done before overwrite
#pragma unroll
    for (int rg = 0; rg < 4; rg++) {
        int nl = q * 4 + rg;
        float pre = acch[rg] + bhv;
        float th = 2.f / (1.f + __expf(-2.f * pre)) - 1.f;
        float hv = hvreg[rg];
        xs_t[nl][ch] = hv + zreg[rg] * (th - hv);   // stage h' for coalesced write
    }
    __syncthreads();
    {
        int f = tid * 4;                      // 1024 floats = 16 nodes x 64
        int nl = f >> 6, c = f & 63;
        float4 v = *(const float4*)&xs_t[nl][c];
        int gi = ((base + nl) << 6) | c;
        *(float4*)&h[gi] = v;
        __half2 p0 = {__float2half(v.x), __float2half(v.y)};
        __half2 p1 = {__float2half(v.z), __float2half(v.w)};
        *(__half2*)&h16o[gi] = p0;
        *(__half2*)&h16o[gi + 2] = p1;
    }
}

// ---------------- output: out = h @ Wo^T + bo ----------------
__global__ void out_kernel(const float* __restrict__ h, const float* __restrict__ Wo,
                           const float* __restrict__ bo, float* __restrict__ out) {
    int wid = (blockIdx.x * blockDim.x + threadIdx.x) >> 6;
    int l = threadIdx.x & 63;
    if (wid >= NODES) return;
    float p = h[(wid << 6) | l] * Wo[l];
#pragma unroll
    for (int off = 32; off > 0; off >>= 1) p += __shfl_down(p, off);
    if (l == 0) out[wid] = p + bo[0];
}

extern "C" void kernel_launch(void* const* d_in, const int* in_sizes, int n_in,
                              void* d_out, int out_size, void* d_ws, size_t ws_size,
                              hipStream_t stream) {
    const float* attr = (const float*)d_in[0];
    const float* adj  = (const float*)d_in[1];
    const float* Wi   = (const float*)d_in[2];
    const float* bi   = (const float*)d_in[3];
    const float* Wz   = (const float*)d_in[4];
    const float* bz   = (const float*)d_in[5];
    const float* Wr   = (const float*)d_in[6];
    const float* br   = (const float*)d_in[7];
    const float* Wh   = (const float*)d_in[8];
    const float* bh   = (const float*)d_in[9];
    const float* Wo   = (const float*)d_in[10];
    const float* bo   = (const float*)d_in[11];
    float* out = (float*)d_out;

    char* ws = (char*)d_ws;
    size_t off = 0;
    auto carve = [&](size_t bytes) { void* p = ws + off; off = (off + bytes + 255) & ~(size_t)255; return p; };
    float* h      = (float*)carve((size_t)NODES * HD * 4);            // 8.4 MB
    __half* h16a  = (__half*)carve((size_t)(NODES + 1) * HD * 2);     // 4.2 MB (+dummy row)
    __half* h16b  = (__half*)carve((size_t)(NODES + 1) * HD * 2);     // 4.2 MB (+dummy row)
    _Float16* wf_hi = (_Float16*)carve(3 * 4 * 6 * 64 * 8 * 2);       // 73.7 KB
    _Float16* wf_lo = (_Float16*)carve(3 * 4 * 6 * 64 * 8 * 2);       // 73.7 KB
    int* cnt_in   = (int*)carve((size_t)NODES * 4);
    int* cnt_out  = (int*)carve((size_t)NODES * 4);
    int* edge_in  = (int*)carve((size_t)NODES * ECAP * 4);            // 12.6 MB
    int* edge_out = (int*)carve((size_t)NODES * ECAP * 4);            // 12.6 MB

    hipMemsetAsync(cnt_out, 0, (size_t)NODES * 4, stream);            // cnt_in needs no memset

    init_h_kernel<<<((NODES + 1) * HD + 255) / 256, 256, 0, stream>>>(attr, Wi, bi, h, h16a, h16b);
    wprep_kernel<<<(3 * 4 * 6 * 64 * 8 + 255) / 256, 256, 0, stream>>>(Wz, Wr, Wh, wf_hi, wf_lo);
    count_rows_kernel<<<NODES / 4, 256, 0, stream>>>((const float4*)adj, cnt_in, edge_in,
                                                     cnt_out, edge_out);

    for (int step = 0; step < STEPS; ++step) {
        const __half* hin = (step & 1) ? h16b : h16a;
        __half* hout      = (step & 1) ? h16a : h16b;
        step_kernel<<<NODES / 16, 256, 0, stream>>>(
            (const uint4*)hin, cnt_in, edge_in, cnt_out, edge_out,
            wf_hi, wf_lo, bz, br, bh, h, hout);
    }
    out_kernel<<<NODES * HD / 256, 256, 0, stream>>>(h, Wo, bo, out);
}